// Round 5
// baseline (99.994 us; speedup 1.0000x reference)
//
#include <hip/hip_runtime.h>
#include <math.h>

// Problem constants (from reference setup_inputs): B=32, N=256, D=32.
#define BB 32
#define NN 256
#define DD 32
#define IS 8                      // i-splits: 8 chunks of 32 rows
#define IC (NN / IS)              // 32 i-rows per block (= readlane sources)
#define JC 4                      // j-chunks of 64 (one j-row per lane)
#define NPART (BB * 3 * JC * IS)  // 3072 blocks / partials
#define PART_OFF 64               // float offset of partials within ws

__device__ __forceinline__ float rdlane(float v, int l) {
    return __int_as_float(__builtin_amdgcn_readlane(__float_as_int(v), l));
}

__global__ void mmd_init(unsigned int* cnt) { *cnt = 0u; }

// One wave per block. Lane holds: its j-row (32 regs) + an i-row (32 regs).
// Inner loop is pure register math: i-row broadcast via v_readlane (SGPR
// operand into v_fmac) — zero LDS / zero memory on the critical path.
// type 0: (x,x) +1 | type 1: (y,y) +1 | type 2: (x,y) -2
__global__ __launch_bounds__(64) void mmd_fused(
    const float* __restrict__ x, const float* __restrict__ y,
    const float* __restrict__ w, float* __restrict__ ws,
    float* __restrict__ out) {
    unsigned int* cnt = (unsigned int*)ws;
    float* partials = ws + PART_OFF;

    const int blk  = blockIdx.x;
    const int is   = blk & (IS - 1);
    const int jc   = (blk >> 3) & (JC - 1);
    const int bt   = blk >> 5;
    const int type = bt % 3;
    const int b    = bt / 3;
    const int lane = threadIdx.x;

    const float* Irows = (type == 1) ? y : x;   // rows (i), broadcast side
    const float* Jrows = (type == 0) ? x : y;   // cols (j), per-lane side

    // Load per-lane rows (lanes 32..63 duplicate i-rows of lanes 0..31 —
    // same addresses, coalesced, readlane only uses lanes 0..31).
    float ai[DD], bj[DD];
    {
        const float4* ir = (const float4*)(
            Irows + ((size_t)(b * NN + is * IC + (lane & (IC - 1)))) * DD);
        const float4* jr = (const float4*)(
            Jrows + ((size_t)(b * NN + jc * 64 + lane)) * DD);
        #pragma unroll
        for (int k = 0; k < DD / 4; ++k) {
            float4 va = ir[k];
            ai[4 * k + 0] = va.x; ai[4 * k + 1] = va.y;
            ai[4 * k + 2] = va.z; ai[4 * k + 3] = va.w;
            float4 vb = jr[k];
            bj[4 * k + 0] = vb.x; bj[4 * k + 1] = vb.y;
            bj[4 * k + 2] = vb.z; bj[4 * k + 3] = vb.w;
        }
    }

    // Self-products with the IDENTICAL 4-chain structure as the dot loop:
    // guarantees sq == exact 0 on the xx/yy diagonal before the clamp.
    float a2l, b2;
    {
        float c0 = 0.f, c1 = 0.f, c2 = 0.f, c3 = 0.f;
        float d0 = 0.f, d1 = 0.f, d2 = 0.f, d3 = 0.f;
        #pragma unroll
        for (int k = 0; k < DD; k += 4) {
            c0 = fmaf(ai[k + 0], ai[k + 0], c0);
            c1 = fmaf(ai[k + 1], ai[k + 1], c1);
            c2 = fmaf(ai[k + 2], ai[k + 2], c2);
            c3 = fmaf(ai[k + 3], ai[k + 3], c3);
            d0 = fmaf(bj[k + 0], bj[k + 0], d0);
            d1 = fmaf(bj[k + 1], bj[k + 1], d1);
            d2 = fmaf(bj[k + 2], bj[k + 2], d2);
            d3 = fmaf(bj[k + 3], bj[k + 3], d3);
        }
        a2l = (c0 + c1) + (c2 + c3);
        b2  = (d0 + d1) + (d2 + d3);
    }

    const float negw = -w[b] * (1.0f / (float)DD);

    float acc = 0.f;
    #pragma unroll 2
    for (int ii = 0; ii < IC; ++ii) {
        float c0 = 0.f, c1 = 0.f, c2 = 0.f, c3 = 0.f;
        #pragma unroll
        for (int k = 0; k < DD; k += 4) {
            c0 = fmaf(rdlane(ai[k + 0], ii), bj[k + 0], c0);
            c1 = fmaf(rdlane(ai[k + 1], ii), bj[k + 1], c1);
            c2 = fmaf(rdlane(ai[k + 2], ii), bj[k + 2], c2);
            c3 = fmaf(rdlane(ai[k + 3], ii), bj[k + 3], c3);
        }
        const float dot = (c0 + c1) + (c2 + c3);
        float sq = fmaf(-2.0f, dot, rdlane(a2l, ii) + b2);
        sq = fmaxf(sq, 1e-8f);   // folds norm clamp: sqrt(1e-8) = 1e-4
        acc += __expf(negw * __builtin_amdgcn_sqrtf(sq));
    }

    // Deterministic wave64 reduction.
    #pragma unroll
    for (int off = 32; off > 0; off >>= 1) acc += __shfl_down(acc, off, 64);

    // Publish partial + last-block finale (agent scope; deterministic value:
    // the finale reads ALL partials in a fixed order regardless of which
    // block executes it).
    unsigned int old = 0u;
    if (lane == 0) {
        const float weight = (type == 2) ? -2.0f : 1.0f;
        const float scale  = weight / ((float)NN * (float)NN * (float)BB);
        __hip_atomic_store(&partials[blk], acc * scale,
                           __ATOMIC_RELEASE, __HIP_MEMORY_SCOPE_AGENT);
        old = __hip_atomic_fetch_add(cnt, 1u, __ATOMIC_ACQ_REL,
                                     __HIP_MEMORY_SCOPE_AGENT);
    }
    old = (unsigned int)__builtin_amdgcn_readfirstlane((int)old);
    if (old == NPART - 1) {
        double s = 0.0;
        #pragma unroll
        for (int t = 0; t < NPART / 64; ++t) {
            float p = __hip_atomic_load(&partials[lane + (t << 6)],
                                        __ATOMIC_RELAXED,
                                        __HIP_MEMORY_SCOPE_AGENT);
            s += (double)p;
        }
        #pragma unroll
        for (int off = 32; off > 0; off >>= 1) s += __shfl_down(s, off, 64);
        if (lane == 0) out[0] = (float)s;
    }
}

extern "C" void kernel_launch(void* const* d_in, const int* in_sizes, int n_in,
                              void* d_out, int out_size, void* d_ws, size_t ws_size,
                              hipStream_t stream) {
    const float* x = (const float*)d_in[0];
    const float* y = (const float*)d_in[1];
    const float* w = (const float*)d_in[2];
    float* out = (float*)d_out;
    float* ws  = (float*)d_ws;   // [0]: counter, [PART_OFF..]: NPART partials

    mmd_init<<<1, 1, 0, stream>>>((unsigned int*)ws);
    mmd_fused<<<NPART, 64, 0, stream>>>(x, y, w, ws, out);
}

// Round 6
// 63.066 us; speedup vs baseline: 1.5855x; 1.5855x over previous
//
#include <hip/hip_runtime.h>
#include <math.h>

// Problem constants (from reference setup_inputs): B=32, N=256, D=32.
#define BB 32
#define NN 256
#define DD 32
#define RPT 4                    // A-rows per thread (held in registers)
#define TPB 64                   // one wave per block; 64*RPT = 256 rows
#define SPLIT 16                 // j-dimension split per (batch,type)
#define JCHUNK (NN / SPLIT)      // 16 j's per block
#define NPART (BB * 3 * SPLIT)   // 1536 blocks / partials
#define PART_OFF 64              // float offset of partials within ws

__global__ void mmd_init(unsigned int* cnt) { *cnt = 0u; }

// type 0: (x,x) +1 | type 1: (y,y) +1 | type 2: (x,y) -2
// __launch_bounds__(64, 1): min 1 wave/EU -> compiler may use up to 512
// VGPRs. The a[4][8] float4 A-fragment (128 VGPRs) MUST be in registers;
// R1-R5 all silently spilled row data to scratch under the default budget.
__global__ __launch_bounds__(TPB, 1) void mmd_fused(
    const float* __restrict__ x, const float* __restrict__ y,
    const float* __restrict__ w, float* __restrict__ ws,
    float* __restrict__ out) {
    unsigned int* cnt = (unsigned int*)ws;
    float* partials = ws + PART_OFF;

    const int blk  = blockIdx.x;
    const int s    = blk & (SPLIT - 1);
    const int bt   = blk / SPLIT;
    const int type = bt % 3;
    const int b    = bt / 3;
    const int tid  = threadIdx.x;

    const float* Arow_base = (type == 1) ? y : x;   // rows (i)
    const float* Bcol_base = (type == 0) ? x : y;   // cols (j)

    // 4 A-rows per thread in registers, rows i = r*64 + tid.
    float4 a[RPT][DD / 4];
    #pragma unroll
    for (int r = 0; r < RPT; ++r) {
        const float4* ar =
            (const float4*)(Arow_base + ((size_t)b * NN + r * TPB + tid) * DD);
        #pragma unroll
        for (int k = 0; k < DD / 4; ++k) a[r][k] = ar[k];
    }

    // Stage the 16 B-rows in LDS (128 float4 = 2 stores/thread).
    __shared__ float4 bs4[JCHUNK * (DD / 4)];
    __shared__ float b2s[JCHUNK];
    {
        const float4* bb =
            (const float4*)(Bcol_base + ((size_t)b * NN + s * JCHUNK) * DD);
        bs4[tid] = bb[tid];
        bs4[tid + TPB] = bb[tid + TPB];
    }

    float a2[RPT];
    #pragma unroll
    for (int r = 0; r < RPT; ++r) {
        float4 s2 = make_float4(0.f, 0.f, 0.f, 0.f);
        #pragma unroll
        for (int k = 0; k < DD / 4; ++k) {
            float4 v = a[r][k];
            s2.x = fmaf(v.x, v.x, s2.x);
            s2.y = fmaf(v.y, v.y, s2.y);
            s2.z = fmaf(v.z, v.z, s2.z);
            s2.w = fmaf(v.w, v.w, s2.w);
        }
        a2[r] = (s2.x + s2.y) + (s2.z + s2.w);
    }

    __syncthreads();
    if (tid < JCHUNK) {
        float4 s2 = make_float4(0.f, 0.f, 0.f, 0.f);
        #pragma unroll
        for (int k = 0; k < DD / 4; ++k) {
            float4 v = bs4[tid * (DD / 4) + k];
            s2.x = fmaf(v.x, v.x, s2.x);
            s2.y = fmaf(v.y, v.y, s2.y);
            s2.z = fmaf(v.z, v.z, s2.z);
            s2.w = fmaf(v.w, v.w, s2.w);
        }
        b2s[tid] = (s2.x + s2.y) + (s2.z + s2.w);
    }
    __syncthreads();

    const float negw = -w[b] * (1.0f / (float)DD);

    float acc[RPT] = {0.f, 0.f, 0.f, 0.f};
    #pragma unroll 4
    for (int j = 0; j < JCHUNK; ++j) {
        const float b2 = b2s[j];
        float4 dv[RPT];
        #pragma unroll
        for (int r = 0; r < RPT; ++r) dv[r] = make_float4(0.f, 0.f, 0.f, 0.f);
        #pragma unroll
        for (int k = 0; k < DD / 4; ++k) {
            const float4 bv = bs4[j * (DD / 4) + k];   // uniform -> broadcast
            #pragma unroll
            for (int r = 0; r < RPT; ++r) {
                dv[r].x = fmaf(a[r][k].x, bv.x, dv[r].x);
                dv[r].y = fmaf(a[r][k].y, bv.y, dv[r].y);
                dv[r].z = fmaf(a[r][k].z, bv.z, dv[r].z);
                dv[r].w = fmaf(a[r][k].w, bv.w, dv[r].w);
            }
        }
        #pragma unroll
        for (int r = 0; r < RPT; ++r) {
            const float dot = (dv[r].x + dv[r].y) + (dv[r].z + dv[r].w);
            float sq = fmaf(-2.0f, dot, a2[r] + b2);
            sq = fmaxf(sq, 1e-8f);   // folds norm clamp: sqrt(1e-8) = 1e-4
            acc[r] += __expf(negw * __builtin_amdgcn_sqrtf(sq));
        }
    }

    // Deterministic wave64 reduction.
    float tsum = (acc[0] + acc[1]) + (acc[2] + acc[3]);
    #pragma unroll
    for (int off = 32; off > 0; off >>= 1) tsum += __shfl_down(tsum, off, 64);

    // Publish partial + last-block finale (fixed-order double sum —
    // deterministic regardless of which block arrives last).
    unsigned int old = 0u;
    if (tid == 0) {
        const float weight = (type == 2) ? -2.0f : 1.0f;
        const float scale  = weight / ((float)NN * (float)NN * (float)BB);
        __hip_atomic_store(&partials[blk], tsum * scale,
                           __ATOMIC_RELEASE, __HIP_MEMORY_SCOPE_AGENT);
        old = __hip_atomic_fetch_add(cnt, 1u, __ATOMIC_ACQ_REL,
                                     __HIP_MEMORY_SCOPE_AGENT);
    }
    old = (unsigned int)__builtin_amdgcn_readfirstlane((int)old);
    if (old == NPART - 1) {
        double sum = 0.0;
        #pragma unroll
        for (int t = 0; t < NPART / TPB; ++t) {
            float p = __hip_atomic_load(&partials[tid + t * TPB],
                                        __ATOMIC_RELAXED,
                                        __HIP_MEMORY_SCOPE_AGENT);
            sum += (double)p;
        }
        #pragma unroll
        for (int off = 32; off > 0; off >>= 1) sum += __shfl_down(sum, off, 64);
        if (tid == 0) out[0] = (float)sum;
    }
}

extern "C" void kernel_launch(void* const* d_in, const int* in_sizes, int n_in,
                              void* d_out, int out_size, void* d_ws, size_t ws_size,
                              hipStream_t stream) {
    const float* x = (const float*)d_in[0];
    const float* y = (const float*)d_in[1];
    const float* w = (const float*)d_in[2];
    float* out = (float*)d_out;
    float* ws  = (float*)d_ws;   // [0]: counter, [PART_OFF..]: NPART partials

    mmd_init<<<1, 1, 0, stream>>>((unsigned int*)ws);
    mmd_fused<<<NPART, TPB, 0, stream>>>(x, y, w, ws, out);
}